// Round 4
// baseline (152.589 us; speedup 1.0000x reference)
//
#include <hip/hip_runtime.h>
#include <hip/hip_bf16.h>
#include <stdint.h>

#define Bv 2
#define Nv 1000
#define Ev 2000
#define Hv 128
#define Mv 4000  // Bv*Ev

typedef __attribute__((ext_vector_type(8))) short bf16x8;
typedef __attribute__((ext_vector_type(4))) float f32x4;
typedef unsigned short u16;
typedef unsigned int u32;

static __device__ __forceinline__ u32 pack2bf(float a, float b) {
  union { __hip_bfloat162 h; u32 u; } c;
  c.h = __float22bfloat162_rn(make_float2(a, b));
  return c.u;
}
static __device__ __forceinline__ u16 cvt1bf(float a) {
  return (u16)(pack2bf(a, 0.f) & 0xffffu);
}

// bf16x8 * scalar f32 -> bf16x8 (unpack via <<16, mul, repack)
static __device__ __forceinline__ bf16x8 scale_bf8(bf16x8 e, float s) {
  union { bf16x8 v; u32 w[4]; } in, out;
  in.v = e;
#pragma unroll
  for (int i = 0; i < 4; ++i) {
    float lo = __uint_as_float(in.w[i] << 16);
    float hi = __uint_as_float(in.w[i] & 0xffff0000u);
    out.w[i] = pack2bf(lo * s, hi * s);
  }
  return out.v;
}

// edge_network fp32 [H][H][H] -> bf16, same (h,i,j) layout. 2M elems, 8/thread.
__global__ void k_cvt_en(const float* __restrict__ en, u16* __restrict__ enbf) {
  size_t idx = ((size_t)blockIdx.x * 256u + threadIdx.x) * 8u;
  const f32x4* p = (const f32x4*)(en + idx);
  f32x4 a = p[0], b = p[1];
  uint4 o;
  o.x = pack2bf(a.x, a.y);
  o.y = pack2bf(a.z, a.w);
  o.z = pack2bf(b.x, b.y);
  o.w = pack2bf(b.z, b.w);
  *(uint4*)(enbf + idx) = o;
}

// Transpose+convert: src fp32 [R][C] -> dst bf16 [C][Rpad], zero-filled rows R..Rpad.
__global__ void k_tr_cvt(const float* __restrict__ src, u16* __restrict__ dst,
                         int R, int C, int Rpad) {
  __shared__ float tile[32][33];
  const int z = blockIdx.z;
  src += (size_t)z * R * C;
  dst += (size_t)z * C * Rpad;
  const int r0 = blockIdx.x * 32, c0 = blockIdx.y * 32;
  const int tx = threadIdx.x & 31, ty = threadIdx.x >> 5;
#pragma unroll
  for (int rr = 0; rr < 4; ++rr) {
    int r = r0 + ty + rr * 8;
    int c = c0 + tx;
    float v = (r < R && c < C) ? src[(size_t)r * C + c] : 0.f;
    tile[ty + rr * 8][tx] = v;
  }
  __syncthreads();
#pragma unroll
  for (int rr = 0; rr < 4; ++rr) {
    int oc = c0 + ty + rr * 8;  // dst row = src col
    int orr = r0 + tx;          // dst col = src row
    if (oc < C)
      dst[(size_t)oc * Rpad + orr] = cvt1bf(tile[tx][ty + rr * 8]);
  }
}

// Split-K GEMM partial: Cacc[m,i] += sum_{k in chunk} A[m,k]*BT[i,k]
template <int M, int KREAL, int KPAD, bool ROWSUM>
__launch_bounds__(256, 4)
__global__ void k_gemm_split(const float* __restrict__ A, const u16* __restrict__ BT,
                             float* __restrict__ Cacc, float* __restrict__ nrmacc) {
  __shared__ u16 AL[64 * 136];
  __shared__ float rowsum[64];
  const int b = blockIdx.z;
  A    += (size_t)b * M * KREAL;
  BT   += (size_t)b * 128 * KPAD;
  Cacc += (size_t)b * M * 128;
  if (ROWSUM) nrmacc += (size_t)b * M;
  const int t = threadIdx.x;
  const int lane = t & 63;
  const int w = t >> 6;
  const int row16 = lane & 15;
  const int kg = lane >> 4;
  const int mrow0 = blockIdx.x * 64;
  const int kc = blockIdx.y * 128;
  const int mtg = (w >> 1) * 2;
  const int itg = (w & 1) * 4;
  f32x4 acc[2][4];
#pragma unroll
  for (int i = 0; i < 2; ++i)
#pragma unroll
    for (int j = 0; j < 4; ++j) acc[i][j] = (f32x4){0.f, 0.f, 0.f, 0.f};
  if (ROWSUM && t < 64) rowsum[t] = 0.f;
  __syncthreads();
#pragma unroll
  for (int r = 0; r < 4; ++r) {
    const int chunk = t + r * 256;
    const int m = chunk >> 4;
    const int jc = (chunk & 15) * 8;
    const int gm = mrow0 + m;
    const int gk = kc + jc;
    f32x4 x0 = {0.f, 0.f, 0.f, 0.f}, x1 = {0.f, 0.f, 0.f, 0.f};
    if (gm < M && gk + 8 <= KREAL) {
      const f32x4* p = (const f32x4*)(A + (size_t)gm * KREAL + gk);
      x0 = p[0];
      x1 = p[1];
    }
    if (ROWSUM) {
      float s8 = x0.x + x0.y + x0.z + x0.w + x1.x + x1.y + x1.z + x1.w;
      s8 += __shfl_down(s8, 8, 16);
      s8 += __shfl_down(s8, 4, 16);
      s8 += __shfl_down(s8, 2, 16);
      s8 += __shfl_down(s8, 1, 16);
      if ((lane & 15) == 0) rowsum[m] += s8;
    }
    uint4 o;
    o.x = pack2bf(x0.x, x0.y);
    o.y = pack2bf(x0.z, x0.w);
    o.z = pack2bf(x1.x, x1.y);
    o.w = pack2bf(x1.z, x1.w);
    *(uint4*)&AL[m * 136 + jc] = o;
  }
  __syncthreads();
#pragma unroll
  for (int kk = 0; kk < 4; ++kk) {
    bf16x8 a[2], bfr[4];
#pragma unroll
    for (int q = 0; q < 2; ++q)
      a[q] = *(const bf16x8*)&AL[((mtg + q) * 16 + row16) * 136 + kk * 32 + kg * 8];
#pragma unroll
    for (int q = 0; q < 4; ++q)
      bfr[q] = *(const bf16x8*)(BT + (size_t)((itg + q) * 16 + row16) * KPAD + kc + kk * 32 + kg * 8);
#pragma unroll
    for (int mi = 0; mi < 2; ++mi)
#pragma unroll
      for (int ii = 0; ii < 4; ++ii)
        acc[mi][ii] = __builtin_amdgcn_mfma_f32_16x16x32_bf16(a[mi], bfr[ii], acc[mi][ii], 0, 0, 0);
  }
  if (ROWSUM && t < 64 && mrow0 + t < M) atomicAdd(&nrmacc[mrow0 + t], rowsum[t]);
#pragma unroll
  for (int mi = 0; mi < 2; ++mi) {
#pragma unroll
    for (int r = 0; r < 4; ++r) {
      const int lrow = (mtg + mi) * 16 + kg * 4 + r;
      const int gm = mrow0 + lrow;
      if (gm < M) {
#pragma unroll
        for (int ii = 0; ii < 4; ++ii)
          atomicAdd(&Cacc[(size_t)gm * 128 + (itg + ii) * 16 + row16], acc[mi][ii][r]);
      }
    }
  }
}

// out = (aggacc + ns) / (norm + 1)
__global__ void k_epi(const float* __restrict__ acc, const float* __restrict__ ns,
                      const float* __restrict__ nrm, float* __restrict__ out) {
  const int idx = (blockIdx.x * 256 + threadIdx.x) * 4;
  f32x4 a = *(const f32x4*)(acc + idx);
  f32x4 s = *(const f32x4*)(ns + idx);
  const int row = idx >> 7;
  float inv = 1.f / (nrm[row] + 1.0f);
  *(f32x4*)(out + idx) = (a + s) * inv;
}

// new_n2e[m,i] += sum_{h in group} sum_j (ev[m,h]*emb[m,j]) * EN[h,i,j]
// v2: stage emb (bf16) + ev slice ONCE; barrier-free h-loop with in-register
// per-row ev scaling of A-fragments. Grid (32 m-tiles, 16 h-groups of 8).
__launch_bounds__(256, 2)
__global__ void k_edge_mix(const float* __restrict__ ev, const float* __restrict__ emb,
                           const u16* __restrict__ enbf, float* __restrict__ newe) {
  __shared__ u16 U[128 * 136];     // emb bf16, row stride 136
  __shared__ float EVL[128 * 12];  // ev slice [m][h0..h0+8], row stride 12
  const int t = threadIdx.x;
  const int lane = t & 63;
  const int w = t >> 6;
  const int row16 = lane & 15;
  const int kg = lane >> 4;
  const int mb = blockIdx.x * 128;
  const int h0 = blockIdx.y * 8;
  const int mtg = (w >> 1) * 4;
  const int itg = (w & 1) * 4;

  // ---- one-time stage: emb[mb..+128][0..128] f32 -> bf16 U ----
#pragma unroll
  for (int r = 0; r < 8; ++r) {
    const int chunk = t + r * 256;
    const int m = chunk >> 4;
    const int jc = (chunk & 15) * 8;
    const int gm = mb + m;
    f32x4 x0 = {0.f, 0.f, 0.f, 0.f}, x1 = {0.f, 0.f, 0.f, 0.f};
    if (gm < Mv) {
      const f32x4* p = (const f32x4*)(emb + (size_t)gm * Hv + jc);
      x0 = p[0];
      x1 = p[1];
    }
    uint4 o;
    o.x = pack2bf(x0.x, x0.y);
    o.y = pack2bf(x0.z, x0.w);
    o.z = pack2bf(x1.x, x1.y);
    o.w = pack2bf(x1.z, x1.w);
    *(uint4*)&U[m * 136 + jc] = o;
  }
  // ---- one-time stage: ev[mb..+128][h0..h0+8] f32 -> EVL ----
  if (t < 128) {
    const int gm = mb + t;
    f32x4 e0 = {0.f, 0.f, 0.f, 0.f}, e1 = {0.f, 0.f, 0.f, 0.f};
    if (gm < Mv) {
      const f32x4* p = (const f32x4*)(ev + (size_t)gm * Hv + h0);
      e0 = p[0];
      e1 = p[1];
    }
    *(f32x4*)&EVL[t * 12 + 0] = e0;
    *(f32x4*)&EVL[t * 12 + 4] = e1;
  }
  __syncthreads();

  f32x4 acc[4][4];
#pragma unroll
  for (int i = 0; i < 4; ++i)
#pragma unroll
    for (int j = 0; j < 4; ++j) acc[i][j] = (f32x4){0.f, 0.f, 0.f, 0.f};

#pragma unroll 2
  for (int hh = 0; hh < 8; ++hh) {
    float evq[4];
#pragma unroll
    for (int q = 0; q < 4; ++q)
      evq[q] = EVL[((mtg + q) * 16 + row16) * 12 + hh];
    const u16* __restrict__ ben = enbf + (size_t)(h0 + hh) * 16384;
#pragma unroll
    for (int kk = 0; kk < 4; ++kk) {
      bf16x8 a[4], bfr[4];
#pragma unroll
      for (int q = 0; q < 4; ++q) {
        bf16x8 e = *(const bf16x8*)&U[((mtg + q) * 16 + row16) * 136 + kk * 32 + kg * 8];
        a[q] = scale_bf8(e, evq[q]);
      }
#pragma unroll
      for (int q = 0; q < 4; ++q)
        bfr[q] = *(const bf16x8*)(ben + (size_t)((itg + q) * 16 + row16) * 128 + kk * 32 + kg * 8);
#pragma unroll
      for (int mi = 0; mi < 4; ++mi)
#pragma unroll
        for (int ii = 0; ii < 4; ++ii)
          acc[mi][ii] = __builtin_amdgcn_mfma_f32_16x16x32_bf16(a[mi], bfr[ii], acc[mi][ii], 0, 0, 0);
    }
  }
#pragma unroll
  for (int mi = 0; mi < 4; ++mi) {
#pragma unroll
    for (int r = 0; r < 4; ++r) {
      const int gm = mb + (mtg + mi) * 16 + kg * 4 + r;
      if (gm < Mv) {
#pragma unroll
        for (int ii = 0; ii < 4; ++ii)
          atomicAdd(&newe[(size_t)gm * Hv + (itg + ii) * 16 + row16], acc[mi][ii][r]);
      }
    }
  }
}

extern "C" void kernel_launch(void* const* d_in, const int* in_sizes, int n_in,
                              void* d_out, int out_size, void* d_ws, size_t ws_size,
                              hipStream_t stream) {
  const float* ns  = (const float*)d_in[0];  // node_state  [B][N][H]
  const float* ev  = (const float*)d_in[1];  // edge_vec    [B][E][H]
  const float* n2e = (const float*)d_in[2];  // node2edge   [B][E][N]
  const float* e2n = (const float*)d_in[3];  // edge2node   [B][N][E]
  const float* en  = (const float*)d_in[4];  // edge_network[H][H][H]
  float* out = (float*)d_out;

  char* ws = (char*)d_ws;
  float* embacc  = (float*)(ws);              // [4000][128] f32 — dead after edge_mix
  float* newe    = (float*)(ws + 2048000);    // [4000][128] f32
  float* normacc = (float*)(ws + 4096000);    // [2][1000] f32 (+pad)
  u16*   enbf    = (u16*)  (ws + 4104192);    // [128][128][128] bf16 — dead after edge_mix
  u16*   nsT     = (u16*)  (ws + 8298496);    // [2][128][1024] bf16
  u16*   neweT   = (u16*)  (ws);              // [2][128][2048] bf16 (overlays embacc)
  float* aggacc  = (float*)(ws + 4104192);    // [2][1000][128] f32 (overlays enbf)

  hipMemsetAsync(ws, 0, 4104192, stream);     // zero embacc + newe + normacc
  k_cvt_en <<<dim3(1024),     dim3(256), 0, stream>>>(en, enbf);
  k_tr_cvt <<<dim3(32, 4, 2), dim3(256), 0, stream>>>(ns, nsT, Nv, Hv, 1024);
  k_gemm_split<2000, 1000, 1024, false><<<dim3(32, 8, 2), dim3(256), 0, stream>>>(n2e, nsT, embacc, nullptr);
  k_edge_mix<<<dim3(32, 16), dim3(256), 0, stream>>>(ev, embacc, enbf, newe);
  hipMemsetAsync(aggacc, 0, 1024000, stream);
  k_tr_cvt <<<dim3(64, 4, 2), dim3(256), 0, stream>>>(newe, neweT, Ev, Hv, 2048);
  k_gemm_split<1000, 2000, 2048, true><<<dim3(16, 16, 2), dim3(256), 0, stream>>>(e2n, neweT, aggacc, normacc);
  k_epi<<<dim3(250), dim3(256), 0, stream>>>(aggacc, ns, normacc, out);
}